// Round 1
// 302.176 us; speedup vs baseline: 1.0085x; 1.0085x over previous
//
#include <hip/hip_runtime.h>
#include <hip/hip_bf16.h>
#include <stdint.h>

typedef __bf16 bf16;
typedef __bf16 bf16x8 __attribute__((ext_vector_type(8)));
typedef float floatx4 __attribute__((ext_vector_type(4)));
typedef float floatx8 __attribute__((ext_vector_type(8)));

#define MFMA16(A, B, C) __builtin_amdgcn_mfma_f32_16x16x32_bf16(A, B, C, 0, 0, 0)

constexpr int Sc = 2048, HIDc = 2048, NHc = 32, NKVc = 8, HDc = 64;
constexpr float kScale = 0.125f;   // HD^-0.5
constexpr float kMax = 9.0f;       // static softmax max: |s*scale| <= 8 (|q|=|k|=8)

// async 16B global -> LDS (wave-uniform base + lane*16 on the LDS side)
__device__ __forceinline__ void async16(const bf16* g, bf16* l) {
  __builtin_amdgcn_global_load_lds(
      (const __attribute__((address_space(1))) void*)g,
      (__attribute__((address_space(3))) void*)l, 16, 0, 0);
}

// ---------------------------------------------------------------------------
// f32 -> bf16 conversion for hs + 4 weight matrices (blockIdx.y selects).
// ---------------------------------------------------------------------------
__global__ __launch_bounds__(256)
void cvt5(const float* __restrict__ s0, bf16* __restrict__ d0, int n0,
          const float* __restrict__ s1, bf16* __restrict__ d1, int n1,
          const float* __restrict__ s2, bf16* __restrict__ d2, int n2,
          const float* __restrict__ s3, bf16* __restrict__ d3, int n3,
          const float* __restrict__ s4, bf16* __restrict__ d4, int n4)
{
  const float* s; bf16* d; int n;
  switch (blockIdx.y) {
    case 0: s = s0; d = d0; n = n0; break;
    case 1: s = s1; d = d1; n = n1; break;
    case 2: s = s2; d = d2; n = n2; break;
    case 3: s = s3; d = d3; n = n3; break;
    default: s = s4; d = d4; n = n4; break;
  }
  const size_t stride = (size_t)gridDim.x * blockDim.x * 8;
  for (size_t i = ((size_t)blockIdx.x * blockDim.x + threadIdx.x) * 8;
       i < (size_t)n; i += stride) {
    floatx8 f = *(const floatx8*)(s + i);
    bf16x8 o;
#pragma unroll
    for (int j = 0; j < 8; ++j) o[j] = (bf16)f[j];
    *(bf16x8*)(d + i) = o;
  }
}

// ---------------------------------------------------------------------------
// 8-phase pipelined GEMM: C(MxN) = A(MxK) @ Bw(NxK)^T, bf16 in, fp32 accum.
// BK=64 split into two K-halves staged as separate [rows][32] LDS images
// (64B row stride -> ds_read_b128 frags sit at the bank floor, no swizzle).
// 8 waves (2M x 4N), 512 threads. 4 phases per K-tile = (mh, kk) quadrants:
//   {ds_read frags ; issue 1 half-tile global_load_lds ; barrier ;
//    setprio(1) MFMA setprio(0) ; barrier}
// Staging schedule (tile t, slot s = t&1):
//   P1: AK1(t+1 -> s^1)   P2: BK1(t+1 -> s^1)
//   P3: AK0(t+2 -> s)     P4: BK0(t+2 -> s)
// One counted vmcnt gate per tile at P4 (leaves P3+P4 in flight = GATE
// loads, never 0): certifies exactly tile t+1's four halves.
// ---------------------------------------------------------------------------
template<int BM, int BN, bool CF32>
__device__ __forceinline__
void gemm8p(const bf16* __restrict__ A, const bf16* __restrict__ Bw,
            void* __restrict__ C, int N, int K, int m0, int n0,
            bf16* __restrict__ lds)
{
  constexpr int MR2  = BM / 64;     // m-tiles per phase per wave
  constexpr int ALD  = BM / 128;    // global_load_lds per thread per A-half
  constexpr int BLD  = BN / 128;
  constexpr int AH   = BM * 32;     // elements per A K-half image
  constexpr int BH   = BN * 32;
  constexpr int GATE = ALD + BLD;   // loads left in flight at each tile gate

  const int tid  = threadIdx.x;
  const int lane = tid & 63;
  const int w    = tid >> 6;
  const int r    = lane & 15;
  const int quad = lane >> 4;
  const int wm   = w >> 2;          // 2 wave rows
  const int wn   = w & 3;           // 4 wave cols
  const int NT   = K >> 6;

  // per-thread staging sources: chunk = i*512+tid -> (row=chunk/4, col8=chunk%4)
  const bf16* gA[ALD]; const bf16* gB[BLD];
#pragma unroll
  for (int i = 0; i < ALD; ++i) {
    const int ch = i * 512 + tid;
    gA[i] = A + (size_t)(m0 + (ch >> 2)) * K + (ch & 3) * 8;
  }
#pragma unroll
  for (int i = 0; i < BLD; ++i) {
    const int ch = i * 512 + tid;
    gB[i] = Bw + (size_t)(n0 + (ch >> 2)) * K + (ch & 3) * 8;
  }

  auto stA = [&](int kt, int s, int kk) {
    bf16* dst = lds + (s * 2 + kk) * AH + tid * 8;
#pragma unroll
    for (int i = 0; i < ALD; ++i)
      async16(gA[i] + kt * 64 + kk * 32, dst + i * 4096);
  };
  auto stB = [&](int kt, int s, int kk) {
    bf16* dst = lds + 4 * AH + (s * 2 + kk) * BH + tid * 8;
#pragma unroll
    for (int i = 0; i < BLD; ++i)
      async16(gB[i] + kt * 64 + kk * 32, dst + i * 4096);
  };

  const int aoff = (wm * (BM / 2) + r) * 32 + quad * 8;
  const int boff = (wn * 64 + r) * 32 + quad * 8;

  floatx4 acc[2 * MR2][4] = {};
  bf16x8 a[MR2], b[4];

#define LDB(S, KK) do { const bf16* _p = lds + 4 * AH + ((S) * 2 + (KK)) * BH + boff; \
  _Pragma("unroll") for (int n2 = 0; n2 < 4; ++n2) b[n2] = *(const bf16x8*)(_p + n2 * 512); } while (0)
#define LDA(S, KK, MH) do { const bf16* _p = lds + ((S) * 2 + (KK)) * AH + aoff + (MH) * (MR2 * 512); \
  _Pragma("unroll") for (int m2 = 0; m2 < MR2; ++m2) a[m2] = *(const bf16x8*)(_p + m2 * 512); } while (0)
#define MM(MH) do { __builtin_amdgcn_s_setprio(1); \
  _Pragma("unroll") for (int m2 = 0; m2 < MR2; ++m2) \
    _Pragma("unroll") for (int n2 = 0; n2 < 4; ++n2) \
      acc[(MH) * MR2 + m2][n2] = MFMA16(a[m2], b[n2], acc[(MH) * MR2 + m2][n2]); \
  __builtin_amdgcn_s_setprio(0); } while (0)
#define BAR() asm volatile("s_barrier" ::: "memory")
#define GATEW() do { if constexpr (GATE == 4) asm volatile("s_waitcnt vmcnt(4)" ::: "memory"); \
                     else                     asm volatile("s_waitcnt vmcnt(3)" ::: "memory"); } while (0)

  // prologue: tile0 complete + tile1's K0 halves; certify tile0, leave tile1-K0 in flight
  stA(0, 0, 0); stB(0, 0, 0); stA(0, 0, 1); stB(0, 0, 1);
  stA(1, 1, 0); stB(1, 1, 0);
  GATEW(); BAR();

  for (int t = 0; t < NT; ++t) {
    const int s = t & 1;
    // P1 (mh0, kk0)
    LDB(s, 0); LDA(s, 0, 0);
    if (t + 1 < NT) stA(t + 1, s ^ 1, 1);
    BAR(); MM(0); BAR();
    // P2 (mh1, kk0) -- b[] reused
    LDA(s, 0, 1);
    if (t + 1 < NT) stB(t + 1, s ^ 1, 1);
    BAR(); MM(1); BAR();
    // P3 (mh0, kk1)
    LDB(s, 1); LDA(s, 1, 0);
    if (t + 2 < NT) stA(t + 2, s, 0);
    BAR(); MM(0); BAR();
    // P4 (mh1, kk1)
    LDA(s, 1, 1);
    if (t + 2 < NT) stB(t + 2, s, 0);
    BAR(); MM(1);
    GATEW(); BAR();
  }

#undef LDB
#undef LDA
#undef MM
#undef BAR
#undef GATEW

  // epilogue
#pragma unroll
  for (int mt = 0; mt < 2 * MR2; ++mt) {
#pragma unroll
    for (int nt = 0; nt < 4; ++nt) {
      const int row = m0 + wm * (BM / 2) + mt * 16 + quad * 4;
      const int col = n0 + wn * 64 + nt * 16 + r;
#pragma unroll
      for (int g = 0; g < 4; ++g) {
        const size_t ci = (size_t)(row + g) * N + col;
        const float v = acc[mt][nt][g];
        if constexpr (CF32) ((float*)C)[ci] = v;
        else                ((bf16*)C)[ci]  = (bf16)v;
      }
    }
  }
}

__global__ __launch_bounds__(512, 2)
void qkv_gemm8(const bf16* __restrict__ hs,
               const bf16* __restrict__ Wq, const bf16* __restrict__ Wk,
               const bf16* __restrict__ Wv,
               bf16* __restrict__ q_ws, bf16* __restrict__ k_ws,
               bf16* __restrict__ v_ws)
{
  __shared__ bf16 lds[2 * 2 * (256 + 256) * 32];   // 128 KiB
  const int wg  = blockIdx.x;
  const int swz = (wg & 7) * 24 + (wg >> 3);       // 192 blocks, bijective (192%8==0)
  const int mi  = swz / 12, ni = swz % 12;
  const bf16* Bw; bf16* C; int N, n0;
  if (ni < 8)       { Bw = Wq; C = q_ws; N = 2048; n0 = ni * 256; }
  else if (ni < 10) { Bw = Wk; C = k_ws; N = 512;  n0 = (ni - 8) * 256; }
  else              { Bw = Wv; C = v_ws; N = 512;  n0 = (ni - 10) * 256; }
  gemm8p<256, 256, false>(hs, Bw, C, N, HIDc, mi * 256, n0, lds);
}

__global__ __launch_bounds__(512, 2)
void o_gemm8(const bf16* __restrict__ a_ws, const bf16* __restrict__ Wo,
             float* __restrict__ out)
{
  __shared__ bf16 lds[2 * 2 * (128 + 256) * 32];   // 96 KiB
  const int wg  = blockIdx.x;
  const int swz = (wg & 7) * 32 + (wg >> 3);       // 256 blocks = 1/CU
  const int mi  = swz >> 3, ni = swz & 7;
  gemm8p<128, 256, true>(a_ws, Wo, out, HIDc, NHc * HDc, mi * 128, ni * 256, lds);
}

// ---------------------------------------------------------------------------
// RMSNorm + RoPE for K only (Q is fused into attn_fwd). One block per token.
// ---------------------------------------------------------------------------
__global__ __launch_bounds__(256)
void norm_rope_k(bf16* __restrict__ kk, const float* __restrict__ kw,
                 const float* __restrict__ cp, const float* __restrict__ sp)
{
  const int m = blockIdx.x;            // b*S + s
  const int lane = threadIdx.x & 63;   // d
  const int w = threadIdx.x >> 6;
  const float c  = cp[(size_t)m * 64 + lane];
  const float s  = sp[(size_t)m * 64 + lane];
  const float wk = kw[lane];
  for (int h = w; h < NKVc; h += 4) {
    bf16* p = kk + (size_t)m * (NKVc * HDc) + h * HDc + lane;
    float x = (float)*p;
    float ss = x * x;
#pragma unroll
    for (int off = 1; off < 64; off <<= 1) ss += __shfl_xor(ss, off);
    const float rr = rsqrtf(ss * (1.0f / 64.0f) + 1e-6f);
    const float y = wk * x * rr;
    const float partner = __shfl_xor(y, 32);
    const float rot = (lane < 32) ? -partner : partner;
    *p = (bf16)(y * c + rot * s);
  }
}

// ---------------------------------------------------------------------------
// V transpose: v_ws [b*S][kvh*64+d] -> vt [((b*8+kvh)*64+d)*2048 + s].
// ---------------------------------------------------------------------------
__global__ __launch_bounds__(256)
void v_transpose(const bf16* __restrict__ v, bf16* __restrict__ vt)
{
  __shared__ bf16 Ts[64 * 64];
  const int bi  = blockIdx.x;          // (b*8 + kvh)*32 + st
  const int st  = bi & 31;
  const int kvh = (bi >> 5) & 7;
  const int b   = bi >> 8;
  const int tid = threadIdx.x;
  for (int seg = tid; seg < 512; seg += 256) {
    const int sr = seg >> 3, dc = (seg & 7) * 8;
    bf16x8 xv = *(const bf16x8*)(v + (size_t)(b * Sc + st * 64 + sr) * (NKVc * HDc)
                                   + kvh * HDc + dc);
#pragma unroll
    for (int i = 0; i < 8; ++i)
      Ts[(dc + i) * 64 + (sr ^ dc)] = xv[i];
  }
  __syncthreads();
  for (int seg = tid; seg < 512; seg += 256) {
    const int d = seg >> 3, sc = (seg & 7) * 8;
    bf16x8 yv = *(const bf16x8*)(&Ts[d * 64 + (sc ^ (d & 56))]);
    *(bf16x8*)(vt + ((size_t)((b * NKVc + kvh) * 64 + d)) * Sc + st * 64 + sc) = yv;
  }
}

// ---------------------------------------------------------------------------
// Causal flash attention, GQA groups=4, fused Q RMSNorm+RoPE, static-max
// softmax (scores*scale in [-8,8] since RMSNorm fixes |q|=|k|=8; m=9 fixed,
// so no per-tile reductions and no alpha rescaling -- l reduced once at end).
// Block = (b, h, pa) handling q-tiles {31-pa, pa}: constant 33 tile-steps.
// K/V^T staged via async global->LDS with XOR swizzle applied to the GLOBAL
// address (same LDS image as swizzled stores; LDS side stays lane-contiguous).
// o aliases q (each block reads/writes only its own exclusive Q region).
// ---------------------------------------------------------------------------
__global__ __launch_bounds__(256, 4)
void attn_fwd(const bf16* __restrict__ q, const bf16* __restrict__ k,
              const bf16* __restrict__ vt, bf16* __restrict__ o,
              const float* __restrict__ qw, const float* __restrict__ cp,
              const float* __restrict__ sp)
{
  __shared__ bf16 Ks[64 * 64];
  __shared__ bf16 Vs[64 * 64];        // V^T [d][kv], swizzled
  __shared__ bf16 Ps[4][16 * 72];     // per-wave P round-trip, stride 72

  const int bi  = blockIdx.x;
  const int pa  = bi & 15;
  const int h   = (bi >> 4) & 31;
  const int b   = bi >> 9;
  const int kvh = h >> 2;
  const int tid = threadIdx.x, lane = tid & 63, w = tid >> 6;
  const int r = lane & 15, quad = lane >> 4;
  const int qt0 = 31 - pa, qt1 = pa;   // heavy tile first (active all iters)

  // Q load + fused RMSNorm (kScale folded in) + RoPE
  const floatx8 w0 = *(const floatx8*)(qw + quad * 8);
  const floatx8 w1 = *(const floatx8*)(qw + 32 + quad * 8);
  bf16x8 qf[2][2];
#pragma unroll
  for (int t = 0; t < 2; ++t) {
    const int qt = t == 0 ? qt0 : qt1;
    const int m = b * Sc + qt * 64 + w * 16 + r;
    const bf16* qp = q + (size_t)m * (NHc * HDc) + h * HDc + quad * 8;
    bf16x8 x0 = *(const bf16x8*)qp;
    bf16x8 x1 = *(const bf16x8*)(qp + 32);
    float ss = 0.f;
#pragma unroll
    for (int i = 0; i < 8; ++i)
      ss += (float)x0[i] * (float)x0[i] + (float)x1[i] * (float)x1[i];
    ss += __shfl_xor(ss, 16);
    ss += __shfl_xor(ss, 32);
    const float rq = rsqrtf(ss * (1.0f / 64.0f) + 1e-6f) * kScale;
    const floatx8 c0 = *(const floatx8*)(cp + (size_t)m * 64 + quad * 8);
    const floatx8 c1 = *(const floatx8*)(cp + (size_t)m * 64 + 32 + quad * 8);
    const floatx8 s0 = *(const floatx8*)(sp + (size_t)m * 64 + quad * 8);
    const floatx8 s1 = *(const floatx8*)(sp + (size_t)m * 64 + 32 + quad * 8);
    bf16x8 y0v, y1v;
#pragma unroll
    for (int i = 0; i < 8; ++i) {
      const float y0 = (float)x0[i] * rq * w0[i];
      const float y1 = (float)x1[i] * rq * w1[i];
      y0v[i] = (bf16)(y0 * c0[i] - y1 * s0[i]);   // d < 32
      y1v[i] = (bf16)(y1 * c1[i] + y0 * s1[i]);   // d >= 32
    }
    qf[t][0] = y0v; qf[t][1] = y1v;
  }

  floatx4 accO[2][4] = {};
  float lsum[2][4] = {};

  const int kvr = tid >> 3;            // staging row (0..31), +32 for seg1
  const int cA  = (tid & 7) * 8;       // LDS col8 (lane-contiguous dest)
  const int cx  = cA ^ (8 * (kvr & 7));// swizzle on the GLOBAL side
  const int xk  = 8 * (r & 15 & 7);    // read-side XOR: 8*(r&7)

  const bf16* kp = k + (size_t)b * Sc * (NKVc * HDc) + kvh * HDc;
  const bf16* vp = vt + ((size_t)((b * NKVc + kvh) * 64)) * Sc;

  for (int j = 0; j <= qt0; ++j) {
    __syncthreads();
    {
      const bf16* kj = kp + (size_t)j * 64 * (NKVc * HDc);
      const bf16* vj = vp + j * 64;
      async16(kj + (size_t)kvr * (NKVc * HDc) + cx, Ks + tid * 8);
      async16(kj + (size_t)(kvr + 32) * (NKVc * HDc) + cx, Ks + (tid + 256) * 8);
      async16(vj + (size_t)kvr * Sc + cx, Vs + tid * 8);
      async16(vj + (size_t)(kvr + 32) * Sc + cx, Vs + (tid + 256) * 8);
    }
    __syncthreads();

#pragma unroll
    for (int t = 0; t < 2; ++t) {
      if (t == 1 && j > qt1) continue;          // light tile finished
      const int qt = t == 0 ? qt0 : qt1;

      // S = Q K^T (16 x 64 per wave), pre-scaled
      floatx4 sa[4];
#pragma unroll
      for (int nt = 0; nt < 4; ++nt) sa[nt] = floatx4{0.f, 0.f, 0.f, 0.f};
#pragma unroll
      for (int nt = 0; nt < 4; ++nt) {
        const int kv = nt * 16 + r;
        const bf16x8 kb0 = *(const bf16x8*)(&Ks[kv * 64 + ((quad * 8) ^ xk)]);
        const bf16x8 kb1 = *(const bf16x8*)(&Ks[kv * 64 + ((quad * 8 + 32) ^ xk)]);
        sa[nt] = MFMA16(qf[t][0], kb0, sa[nt]);
        sa[nt] = MFMA16(qf[t][1], kb1, sa[nt]);
      }

      // static-max softmax; mask only on the diagonal tile
      const int maskbase = (j == qt) ? (w * 16 + quad * 4) : 1000;
#pragma unroll
      for (int reg = 0; reg < 4; ++reg) {
#pragma unroll
        for (int nt = 0; nt < 4; ++nt) {
          const float p = (nt * 16 + r <= maskbase + reg)
                              ? __expf(sa[nt][reg] - kMax) : 0.f;
          lsum[t][reg] += p;
          Ps[w][(quad * 4 + reg) * 72 + nt * 16 + r] = (bf16)p;
        }
      }

      const bf16x8 pa0 = *(const bf16x8*)(&Ps[w][r * 72 + quad * 8]);
      const bf16x8 pa1 = *(const bf16x8*)(&Ps[w][r * 72 + 32 + quad * 8]);
#pragma unroll
      for (int dt = 0; dt < 4; ++dt) {
        const int d = dt * 16 + r;
        const bf16x8 vb0 = *(const bf16x8*)(&Vs[d * 64 + ((quad * 8) ^ xk)]);
        const bf16x8 vb1 = *(const bf16x8*)(&Vs[d * 64 + ((quad * 8 + 32) ^ xk)]);
        accO[t][dt] = MFMA16(pa0, vb0, accO[t][dt]);
        accO[t][dt] = MFMA16(pa1, vb1, accO[t][dt]);
      }
    }
  }

  // epilogue: reduce l across the 16 column-lanes, divide, write
#pragma unroll
  for (int t = 0; t < 2; ++t) {
    const int qt = t == 0 ? qt0 : qt1;
#pragma unroll
    for (int reg = 0; reg < 4; ++reg) {
      float l = lsum[t][reg];
#pragma unroll
      for (int off = 1; off < 16; off <<= 1) l += __shfl_xor(l, off);
      const float inv = 1.0f / l;
      const size_t row = (size_t)(b * Sc + qt * 64 + w * 16 + quad * 4 + reg);
#pragma unroll
      for (int dt = 0; dt < 4; ++dt)
        o[row * (NHc * HDc) + h * HDc + dt * 16 + r] = (bf16)(accO[t][dt][reg] * inv);
    }
  }
}

// ---------------------------------------------------------------------------
extern "C" void kernel_launch(void* const* d_in, const int* in_sizes, int n_in,
                              void* d_out, int out_size, void* d_ws, size_t ws_size,
                              hipStream_t stream)
{
  const float* hs = (const float*)d_in[0];
  const float* cp = (const float*)d_in[1];
  const float* sp = (const float*)d_in[2];
  const float* Wq = (const float*)d_in[3];
  const float* Wk = (const float*)d_in[4];
  const float* Wv = (const float*)d_in[5];
  const float* Wo = (const float*)d_in[6];
  const float* qw = (const float*)d_in[7];
  const float* kw = (const float*)d_in[8];
  float* out = (float*)d_out;

  char* ws = (char*)d_ws;
  bf16* q_ws  = (bf16*)ws;                      // 16 MiB
  bf16* k_ws  = (bf16*)(ws + (16u << 20));      // 4 MiB
  bf16* v_ws  = (bf16*)(ws + (20u << 20));      // 4 MiB
  bf16* vt_ws = (bf16*)(ws + (24u << 20));      // 4 MiB
  bf16* hs_b  = (bf16*)(ws + (28u << 20));      // 16 MiB
  bf16* Wq_b  = (bf16*)(ws + (44u << 20));      // 8 MiB
  bf16* Wk_b  = (bf16*)(ws + (52u << 20));      // 2 MiB
  bf16* Wv_b  = (bf16*)(ws + (54u << 20));      // 2 MiB
  bf16* Wo_b  = (bf16*)(ws + (56u << 20));      // 8 MiB -> 64 MiB total
  bf16* a_ws  = q_ws;                           // safe alias (see attn_fwd)

  dim3 blk(256);
  cvt5<<<dim3(256, 5), blk, 0, stream>>>(
      hs, hs_b, 4096 * 2048, Wq, Wq_b, 2048 * 2048, Wk, Wk_b, 512 * 2048,
      Wv, Wv_b, 512 * 2048, Wo, Wo_b, 2048 * 2048);
  qkv_gemm8<<<dim3(192), dim3(512), 0, stream>>>(hs_b, Wq_b, Wk_b, Wv_b,
                                                 q_ws, k_ws, v_ws);
  norm_rope_k<<<dim3(4096), blk, 0, stream>>>(k_ws, kw, cp, sp);
  v_transpose<<<dim3(512), blk, 0, stream>>>(v_ws, vt_ws);
  attn_fwd<<<dim3(1024), blk, 0, stream>>>(q_ws, k_ws, vt_ws, a_ws, qw, cp, sp);
  o_gemm8<<<dim3(256), dim3(512), 0, stream>>>(a_ws, Wo_b, out);
}